// Round 2
// baseline (2349.009 us; speedup 1.0000x reference)
//
#include <hip/hip_runtime.h>
#include <math.h>

#define B_TOT 4096
#define T_LEN 200
#define C_IN  16
#define HH    112
#define G4    448     // 4*H
#define NB    8       // batch elements per block
#define HP    116     // padded H (116*4 = 464 bytes, multiple of 16 -> aligned float4 rows)
#define EPS   1e-5f
#define SBLK  256     // stats kernel blocks (fixed; partial layout depends on it)

// ---------------- Kernel 1: per-channel partial sum / sumsq over x [B,T,C] ----------------
// DETERMINISTIC: no float atomics anywhere. Each block writes 32 partials
// (16 sums + 16 sumsqs) to ws[blk*32 + i] via fixed-order shuffle/LDS reduction.
__global__ void stats_kernel(const float* __restrict__ x, float* __restrict__ ws) {
    __shared__ float sm[4][4][8];   // [wave][lanegrp][s0..3,q0..3]
    const int tid = threadIdx.x;

    const float4* __restrict__ x4 = (const float4*)x;
    const int total  = B_TOT * T_LEN * C_IN / 4;   // 3,276,800 float4s
    const int stride = SBLK * 256;                 // 65536 -> exactly 50 iters/thread
    const int i0 = blockIdx.x * 256 + tid;

    float s0=0.f,s1=0.f,s2=0.f,s3=0.f;
    float q0=0.f,q1=0.f,q2=0.f,q3=0.f;
    for (int i = i0; i < total; i += stride) {
        float4 v = x4[i];
        s0 += v.x; q0 += v.x*v.x;
        s1 += v.y; q1 += v.y*v.y;
        s2 += v.z; q2 += v.z*v.z;
        s3 += v.w; q3 += v.w*v.w;
    }
    // butterfly over lanes differing in bits 2..5 (channel phase = lane&3 preserved)
    #pragma unroll
    for (int off = 4; off < 64; off <<= 1) {
        s0 += __shfl_xor(s0, off); q0 += __shfl_xor(q0, off);
        s1 += __shfl_xor(s1, off); q1 += __shfl_xor(q1, off);
        s2 += __shfl_xor(s2, off); q2 += __shfl_xor(q2, off);
        s3 += __shfl_xor(s3, off); q3 += __shfl_xor(q3, off);
    }
    const int lane = tid & 63, wave = tid >> 6;
    if (lane < 4) {
        sm[wave][lane][0] = s0; sm[wave][lane][1] = s1;
        sm[wave][lane][2] = s2; sm[wave][lane][3] = s3;
        sm[wave][lane][4] = q0; sm[wave][lane][5] = q1;
        sm[wave][lane][6] = q2; sm[wave][lane][7] = q3;
    }
    __syncthreads();
    if (tid < 32) {
        const int ch = tid & 15, sq = tid >> 4;
        const int grp = ch >> 2, comp = ch & 3;
        float a = 0.f;
        #pragma unroll
        for (int wv = 0; wv < 4; wv++) a += sm[wv][grp][sq * 4 + comp];
        ws[blockIdx.x * 32 + tid] = a;
    }
}

// ---------------- Kernel 2: fused BN-fold + LSTM recurrence + FC head ----------------
// 512 blocks x 512 threads. Block owns NB=8 batch elements for all 200 steps.
// Threads 0..447: row thread r holds W_hh[r][0:112] + folded W_ih[r][0:16] in VGPRs;
//                 computes z[r][b] for 8 b each step (h read from LDS, broadcast).
// Update phase:   448 threads own 2 (b,j) cells each; c persistent in registers.
// Threads 448..479 prefetch x[t+1] into double-buffered LDS.
__global__ __launch_bounds__(512, 2) void lstm_kernel(
    const float* __restrict__ x,
    const float* __restrict__ gamma, const float* __restrict__ beta,
    const float* __restrict__ W_ih,  const float* __restrict__ W_hh,
    const float* __restrict__ b_ih,  const float* __restrict__ b_hh,
    const float* __restrict__ W_fc,  const float* __restrict__ b_fc,
    const float* __restrict__ ws,    float* __restrict__ out)
{
    __shared__ float stats_s[32];
    __shared__ float scale[16], shift[16];
    __shared__ __align__(16) float hbuf[NB][HP];        // h state, padded rows
    __shared__ __align__(16) float gbuf[4][NB][HP];     // activated gates i,f,g,o
    __shared__ __align__(16) float xbuf[2][NB][C_IN];   // double-buffered x tile

    const int t  = threadIdx.x;
    const int b0 = blockIdx.x * NB;
    const int row = t;

    // Deterministic fixed-order reduction of the 256 per-block partials.
    if (t < 32) {
        float a = 0.f;
        for (int blk = 0; blk < SBLK; blk++) a += ws[blk * 32 + t];
        stats_s[t] = a;
    }
    __syncthreads();
    if (t < 16) {
        const float N = (float)(B_TOT) * (float)(T_LEN);
        const float mean = stats_s[t] / N;
        const float var  = stats_s[16 + t] / N - mean * mean;
        const float sc   = gamma[t] * rsqrtf(var + EPS);
        scale[t] = sc;
        shift[t] = beta[t] - mean * sc;
    }
    for (int i = t; i < NB * HP; i += 512) ((float*)hbuf)[i] = 0.f;
    __syncthreads();

    // Fold BN into per-row weights (register resident for whole kernel)
    float w[HH];    // W_hh row
    float wi[C_IN]; // folded W_ih row
    float bias = 0.f;
    if (row < G4) {
        #pragma unroll
        for (int j = 0; j < HH; j++) w[j] = W_hh[row * HH + j];
        float bb = b_ih[row] + b_hh[row];
        #pragma unroll
        for (int c = 0; c < C_IN; c++) {
            const float wv = W_ih[row * C_IN + c];
            wi[c] = wv * scale[c];
            bb   += wv * shift[c];
        }
        bias = bb;
    } else if (t < G4 + 4 * NB) {
        // stage x tile for step 0
        const int u = t - G4;           // 0..31
        const int b = u >> 2, c4 = u & 3;
        *(float4*)&xbuf[0][b][c4 * 4] =
            *(const float4*)&x[(size_t)(b0 + b) * (T_LEN * C_IN) + 0 * C_IN + c4 * 4];
    }
    __syncthreads();

    // Per-thread constants
    const int gi = (row < G4) ? (row / HH) : 0;    // gate index 0..3 (i,f,g,o)
    const int jr = (row < G4) ? (row % HH) : 0;
    const float mg = (gi == 2) ? 2.f : 1.f;        // tanh = 2*sig(2z)-1
    const float dg = mg - 1.f;
    const int ub = t / 56;                          // update-phase batch (valid t<448)
    const int uj = (t - ub * 56) * 2;               // update-phase j base (even)

    float creg[2] = {0.f, 0.f};                     // cell state for 2 owned cells

    for (int step = 0; step < T_LEN; step++) {
        const int cur = step & 1;
        if (row < G4) {
            float acc[NB];
            #pragma unroll
            for (int b = 0; b < NB; b++) acc[b] = bias;
            #pragma unroll
            for (int bb = 0; bb < NB; bb += 4) {
                // input projection (16 channels)
                #pragma unroll
                for (int c = 0; c < C_IN; c += 4) {
                    float4 xa = *(const float4*)&xbuf[cur][bb+0][c];
                    float4 xb = *(const float4*)&xbuf[cur][bb+1][c];
                    float4 xc = *(const float4*)&xbuf[cur][bb+2][c];
                    float4 xd = *(const float4*)&xbuf[cur][bb+3][c];
                    acc[bb+0] += wi[c]*xa.x + wi[c+1]*xa.y + wi[c+2]*xa.z + wi[c+3]*xa.w;
                    acc[bb+1] += wi[c]*xb.x + wi[c+1]*xb.y + wi[c+2]*xb.z + wi[c+3]*xb.w;
                    acc[bb+2] += wi[c]*xc.x + wi[c+1]*xc.y + wi[c+2]*xc.z + wi[c+3]*xc.w;
                    acc[bb+3] += wi[c]*xd.x + wi[c+1]*xd.y + wi[c+2]*xd.z + wi[c+3]*xd.w;
                }
                // recurrent projection (112 hidden)
                #pragma unroll
                for (int j = 0; j < HH; j += 4) {
                    float4 ha = *(const float4*)&hbuf[bb+0][j];
                    float4 hb = *(const float4*)&hbuf[bb+1][j];
                    float4 hc = *(const float4*)&hbuf[bb+2][j];
                    float4 hd = *(const float4*)&hbuf[bb+3][j];
                    acc[bb+0] += w[j]*ha.x + w[j+1]*ha.y + w[j+2]*ha.z + w[j+3]*ha.w;
                    acc[bb+1] += w[j]*hb.x + w[j+1]*hb.y + w[j+2]*hb.z + w[j+3]*hb.w;
                    acc[bb+2] += w[j]*hc.x + w[j+1]*hc.y + w[j+2]*hc.z + w[j+3]*hc.w;
                    acc[bb+3] += w[j]*hd.x + w[j+1]*hd.y + w[j+2]*hd.z + w[j+3]*hd.w;
                }
            }
            // activation: sigmoid for i,f,o ; tanh for g (branchless via mg/dg)
            #pragma unroll
            for (int b = 0; b < NB; b++) {
                const float z = acc[b];
                const float e = __expf(-mg * z);
                gbuf[gi][b][jr] = mg * __frcp_rn(1.f + e) - dg;
            }
        }
        __syncthreads();

        if (t < G4) {
            // state update for 2 owned cells (contiguous j, same b)
            float2 vi = *(const float2*)&gbuf[0][ub][uj];
            float2 vf = *(const float2*)&gbuf[1][ub][uj];
            float2 vg = *(const float2*)&gbuf[2][ub][uj];
            float2 vo = *(const float2*)&gbuf[3][ub][uj];
            float2 hn;
            {
                float cn = vf.x * creg[0] + vi.x * vg.x; creg[0] = cn;
                hn.x = vo.x * (2.f * __frcp_rn(1.f + __expf(-2.f * cn)) - 1.f);
            }
            {
                float cn = vf.y * creg[1] + vi.y * vg.y; creg[1] = cn;
                hn.y = vo.y * (2.f * __frcp_rn(1.f + __expf(-2.f * cn)) - 1.f);
            }
            *(float2*)&hbuf[ub][uj] = hn;
        } else if (t < G4 + 4 * NB && step + 1 < T_LEN) {
            // prefetch next x tile
            const int u = t - G4;
            const int b = u >> 2, c4 = u & 3;
            *(float4*)&xbuf[1 - cur][b][c4 * 4] =
                *(const float4*)&x[(size_t)(b0 + b) * (T_LEN * C_IN) + (step + 1) * C_IN + c4 * 4];
        }
        __syncthreads();
    }

    // Final FC head: out[b][o] = tanh(b_fc[o] + h[b] . W_fc[o])
    if (t < NB * 6) {
        const int b = t / 6, o = t - b * 6;
        float a = b_fc[o];
        for (int j = 0; j < HH; j++) a += hbuf[b][j] * W_fc[o * HH + j];
        out[(size_t)(b0 + b) * 6 + o] = tanhf(a);
    }
}

extern "C" void kernel_launch(void* const* d_in, const int* in_sizes, int n_in,
                              void* d_out, int out_size, void* d_ws, size_t ws_size,
                              hipStream_t stream) {
    const float* x     = (const float*)d_in[0];
    const float* gamma = (const float*)d_in[1];
    const float* beta  = (const float*)d_in[2];
    const float* W_ih  = (const float*)d_in[3];
    const float* W_hh  = (const float*)d_in[4];
    const float* b_ih  = (const float*)d_in[5];
    const float* b_hh  = (const float*)d_in[6];
    const float* W_fc  = (const float*)d_in[7];
    const float* b_fc  = (const float*)d_in[8];
    float* out = (float*)d_out;
    float* ws  = (float*)d_ws;

    stats_kernel<<<SBLK, 256, 0, stream>>>(x, ws);
    lstm_kernel<<<B_TOT / NB, 512, 0, stream>>>(x, gamma, beta, W_ih, W_hh,
                                                b_ih, b_hh, W_fc, b_fc, ws, out);
}

// Round 3
// 574.926 us; speedup vs baseline: 4.0858x; 4.0858x over previous
//
#include <hip/hip_runtime.h>
#include <math.h>

#define B_TOT 4096
#define T_LEN 200
#define C_IN  16
#define HH    112
#define G4    448
#define NB    16      // batches per block (= MFMA M)
#define EPS   1e-5f
#define SBLK  256     // stats kernel blocks

typedef _Float16 half8  __attribute__((ext_vector_type(8)));
typedef _Float16 half4v __attribute__((ext_vector_type(4)));
typedef float    f32x4  __attribute__((ext_vector_type(4)));

// Split fp32 into fp16 hi + 2^12-scaled fp16 lo. Flush hi if it would be a
// fp16 denormal (MFMA denormal handling unverified); lo then carries the value.
__device__ __forceinline__ void split16(float v, _Float16 &hi, _Float16 &lo) {
    _Float16 h = (_Float16)v;
    float hf = (float)h;
    if (__builtin_fabsf(hf) < 6.103515625e-05f) { h = (_Float16)0.0f; hf = 0.0f; }
    hi = h;
    lo = (_Float16)((v - hf) * 4096.0f);
}

// ---------------- Kernel 1: deterministic per-channel partial sums ----------------
__global__ void stats_kernel(const float* __restrict__ x, float* __restrict__ ws) {
    __shared__ float sm[4][4][8];
    const int tid = threadIdx.x;
    const float4* __restrict__ x4 = (const float4*)x;
    const int total  = B_TOT * T_LEN * C_IN / 4;
    const int stride = SBLK * 256;
    const int i0 = blockIdx.x * 256 + tid;

    float s0=0.f,s1=0.f,s2=0.f,s3=0.f;
    float q0=0.f,q1=0.f,q2=0.f,q3=0.f;
    for (int i = i0; i < total; i += stride) {
        float4 v = x4[i];
        s0 += v.x; q0 += v.x*v.x;
        s1 += v.y; q1 += v.y*v.y;
        s2 += v.z; q2 += v.z*v.z;
        s3 += v.w; q3 += v.w*v.w;
    }
    #pragma unroll
    for (int off = 4; off < 64; off <<= 1) {
        s0 += __shfl_xor(s0, off); q0 += __shfl_xor(q0, off);
        s1 += __shfl_xor(s1, off); q1 += __shfl_xor(q1, off);
        s2 += __shfl_xor(s2, off); q2 += __shfl_xor(q2, off);
        s3 += __shfl_xor(s3, off); q3 += __shfl_xor(q3, off);
    }
    const int lane = tid & 63, wave = tid >> 6;
    if (lane < 4) {
        sm[wave][lane][0] = s0; sm[wave][lane][1] = s1;
        sm[wave][lane][2] = s2; sm[wave][lane][3] = s3;
        sm[wave][lane][4] = q0; sm[wave][lane][5] = q1;
        sm[wave][lane][6] = q2; sm[wave][lane][7] = q3;
    }
    __syncthreads();
    if (tid < 32) {
        const int ch = tid & 15, sq = tid >> 4;
        const int grp = ch >> 2, comp = ch & 3;
        float a = 0.f;
        #pragma unroll
        for (int wv = 0; wv < 4; wv++) a += sm[wv][grp][sq * 4 + comp];
        ws[blockIdx.x * 32 + tid] = a;
    }
}

// ---------------- Kernel 2: MFMA LSTM ----------------
// 256 blocks x 448 threads (7 waves). Wave w owns N-tiles 4w..4w+3 of the
// 448x128 concatenated weight matrix [W_hh | W_ih*scale] as register-resident
// fp16 hi/lo B-fragments. v_t = [h_{t-1}; x_t] lives in LDS in A-fragment order.
__global__ __launch_bounds__(448, 2) void lstm_kernel(
    const float* __restrict__ x,
    const float* __restrict__ gamma, const float* __restrict__ beta,
    const float* __restrict__ W_ih,  const float* __restrict__ W_hh,
    const float* __restrict__ b_ih,  const float* __restrict__ b_hh,
    const float* __restrict__ W_fc,  const float* __restrict__ b_fc,
    const float* __restrict__ ws,    float* __restrict__ out)
{
    __shared__ float stats_s[32];
    __shared__ float scale_s[16], shift_s[16];
    __shared__ __align__(16) _Float16 vbuf[2][4][64][8];   // [hi/lo][ktile][lane][8] A-fragment order
    __shared__ __align__(16) float gbuf[G4][20];           // activated gates [n][b] (+pad)
    __shared__ __align__(16) float hfinal[NB][HH];

    const int u    = threadIdx.x;
    const int lane = u & 63;
    const int wv   = u >> 6;          // wave 0..6
    const int nloc = lane & 15;
    const int q    = lane >> 4;       // 0..3
    const int b0   = blockIdx.x * NB;

    // --- BN stats (deterministic fixed-order reduction) ---
    if (u < 32) {
        float a = 0.f;
        for (int blk = 0; blk < SBLK; ++blk) a += ws[blk * 32 + u];
        stats_s[u] = a;
    }
    __syncthreads();
    if (u < 16) {
        const float N = (float)B_TOT * (float)T_LEN;
        const float mean = stats_s[u] / N;
        const float var  = stats_s[16 + u] / N - mean * mean;
        const float sc   = gamma[u] * rsqrtf(var + EPS);
        scale_s[u] = sc;
        shift_s[u] = beta[u] - mean * sc;
    }
    for (int i = u; i < (int)(sizeof(vbuf) / 4); i += G4) ((int*)vbuf)[i] = 0;
    __syncthreads();

    // --- Build register-resident weight fragments (one-time) ---
    // B-fragment: lane holds W_cat[n = tile*16 + (lane&15)][k = kt*32 + (lane>>4)*8 + j]
    half8 wHI[4][4], wLO[4][4];
    float biasr[4];
    #pragma unroll
    for (int nt = 0; nt < 4; ++nt) {
        const int n = wv * 64 + nt * 16 + nloc;
        #pragma unroll
        for (int kt = 0; kt < 4; ++kt) {
            const int kb = kt * 32 + q * 8;    // multiple of 8; never straddles k=112
            float wtmp[8];
            if (kb < HH) {
                float4 aa = *(const float4*)&W_hh[n * HH + kb];
                float4 bb = *(const float4*)&W_hh[n * HH + kb + 4];
                wtmp[0]=aa.x; wtmp[1]=aa.y; wtmp[2]=aa.z; wtmp[3]=aa.w;
                wtmp[4]=bb.x; wtmp[5]=bb.y; wtmp[6]=bb.z; wtmp[7]=bb.w;
            } else {
                const int c0 = kb - HH;
                float4 aa = *(const float4*)&W_ih[n * C_IN + c0];
                float4 bb = *(const float4*)&W_ih[n * C_IN + c0 + 4];
                wtmp[0]=aa.x*scale_s[c0+0]; wtmp[1]=aa.y*scale_s[c0+1];
                wtmp[2]=aa.z*scale_s[c0+2]; wtmp[3]=aa.w*scale_s[c0+3];
                wtmp[4]=bb.x*scale_s[c0+4]; wtmp[5]=bb.y*scale_s[c0+5];
                wtmp[6]=bb.z*scale_s[c0+6]; wtmp[7]=bb.w*scale_s[c0+7];
            }
            #pragma unroll
            for (int jj = 0; jj < 8; ++jj) {
                _Float16 th, tl;
                split16(wtmp[jj], th, tl);
                wHI[nt][kt][jj] = th;
                wLO[nt][kt][jj] = tl;
            }
        }
        float bb2 = b_ih[n] + b_hh[n];
        #pragma unroll
        for (int c = 0; c < C_IN; ++c) bb2 += W_ih[n * C_IN + c] * shift_s[c];
        biasr[nt] = bb2;
    }

    // --- update-phase mapping: thread u owns (b = u&15, k = 4*(u>>4)..+3) ---
    const int ub   = u & 15;
    const int kb_u = (u >> 4) * 4;            // 0..108
    const int kt_u = kb_u >> 5;
    const int q_u  = (kb_u >> 3) & 3;
    const int j_u  = kb_u & 7;                // 0 or 4
    const int lt_u = ub + 16 * q_u;
    float creg[4] = {0.f, 0.f, 0.f, 0.f};

    // --- x loader mapping (threads 0..63): (b = u>>2, c = 4*(u&3)) ---
    const int xb = u >> 2;
    const int xc = (u & 3) * 4;
    const size_t xbase = (size_t)(b0 + xb) * (T_LEN * C_IN) + xc;
    const int qx  = ((HH + xc) >> 3) & 3;     // 2 or 3
    const int jx  = xc & 7;                   // 0 or 4
    const int ltx = xb + 16 * qx;

    float4 xreg;
    if (u < 64) xreg = *(const float4*)&x[xbase];     // x at t=0
    if (u < 64) {
        half4v xh, xl;
        #pragma unroll
        for (int jj = 0; jj < 4; ++jj) {
            _Float16 th, tl;
            split16(((const float*)&xreg)[jj], th, tl);
            xh[jj] = th; xl[jj] = tl;
        }
        *(half4v*)&vbuf[0][3][ltx][jx] = xh;
        *(half4v*)&vbuf[1][3][ltx][jx] = xl;
    }
    __syncthreads();

    // --- recurrence ---
    for (int step = 0; step < T_LEN; ++step) {
        if (u < 64 && step + 1 < T_LEN)
            xreg = *(const float4*)&x[xbase + (size_t)(step + 1) * C_IN];

        half8 ah[4], al[4];
        #pragma unroll
        for (int kt = 0; kt < 4; ++kt) {
            ah[kt] = *(const half8*)&vbuf[0][kt][lane][0];
            al[kt] = *(const half8*)&vbuf[1][kt][lane][0];
        }
        #pragma unroll
        for (int nt = 0; nt < 4; ++nt) {
            f32x4 ch = {0.f, 0.f, 0.f, 0.f};
            f32x4 cl = {0.f, 0.f, 0.f, 0.f};
            #pragma unroll
            for (int kt = 0; kt < 4; ++kt) {
                ch = __builtin_amdgcn_mfma_f32_16x16x32_f16(ah[kt], wHI[nt][kt], ch, 0, 0, 0);
                cl = __builtin_amdgcn_mfma_f32_16x16x32_f16(al[kt], wHI[nt][kt], cl, 0, 0, 0);
                cl = __builtin_amdgcn_mfma_f32_16x16x32_f16(ah[kt], wLO[nt][kt], cl, 0, 0, 0);
            }
            // D mapping: col(n) = lane&15, row(m=batch) = (lane>>4)*4 + reg
            const int gate = (wv * 4 + nt) / 7;           // 7 N-tiles per gate
            const float mg  = (gate == 2) ? 2.f : 1.f;    // tanh = 2*sig(2z)-1
            const float dgm = mg - 1.f;
            const int n = wv * 64 + nt * 16 + nloc;
            float4 av;
            #pragma unroll
            for (int r = 0; r < 4; ++r) {
                const float z = ch[r] + cl[r] * (1.f / 4096.f) + biasr[nt];
                ((float*)&av)[r] = mg * __frcp_rn(1.f + __expf(-mg * z)) - dgm;
            }
            *(float4*)&gbuf[n][q * 4] = av;
        }
        __syncthreads();

        // ---- state update ----
        {
            float hv[4];
            #pragma unroll
            for (int jj = 0; jj < 4; ++jj) {
                const float iv = gbuf[kb_u + jj][ub];
                const float fv = gbuf[HH + kb_u + jj][ub];
                const float gv = gbuf[2 * HH + kb_u + jj][ub];
                const float ov = gbuf[3 * HH + kb_u + jj][ub];
                const float cn = fv * creg[jj] + iv * gv;
                creg[jj] = cn;
                hv[jj] = ov * (2.f * __frcp_rn(1.f + __expf(-2.f * cn)) - 1.f);
            }
            if (step + 1 < T_LEN) {
                half4v hh, hl;
                #pragma unroll
                for (int jj = 0; jj < 4; ++jj) {
                    _Float16 th, tl;
                    split16(hv[jj], th, tl);
                    hh[jj] = th; hl[jj] = tl;
                }
                *(half4v*)&vbuf[0][kt_u][lt_u][j_u] = hh;
                *(half4v*)&vbuf[1][kt_u][lt_u][j_u] = hl;
                if (u < 64) {
                    half4v xh, xl;
                    #pragma unroll
                    for (int jj = 0; jj < 4; ++jj) {
                        _Float16 th, tl;
                        split16(((const float*)&xreg)[jj], th, tl);
                        xh[jj] = th; xl[jj] = tl;
                    }
                    *(half4v*)&vbuf[0][3][ltx][jx] = xh;
                    *(half4v*)&vbuf[1][3][ltx][jx] = xl;
                }
            } else {
                float4 h4;
                h4.x = hv[0]; h4.y = hv[1]; h4.z = hv[2]; h4.w = hv[3];
                *(float4*)&hfinal[ub][kb_u] = h4;
            }
        }
        __syncthreads();
    }

    // --- FC head ---
    if (u < NB * 6) {
        const int b = u / 6, o = u - b * 6;
        float a = b_fc[o];
        for (int j = 0; j < HH; ++j) a += hfinal[b][j] * W_fc[o * HH + j];
        out[(size_t)(b0 + b) * 6 + o] = tanhf(a);
    }
}

extern "C" void kernel_launch(void* const* d_in, const int* in_sizes, int n_in,
                              void* d_out, int out_size, void* d_ws, size_t ws_size,
                              hipStream_t stream) {
    const float* x     = (const float*)d_in[0];
    const float* gamma = (const float*)d_in[1];
    const float* beta  = (const float*)d_in[2];
    const float* W_ih  = (const float*)d_in[3];
    const float* W_hh  = (const float*)d_in[4];
    const float* b_ih  = (const float*)d_in[5];
    const float* b_hh  = (const float*)d_in[6];
    const float* W_fc  = (const float*)d_in[7];
    const float* b_fc  = (const float*)d_in[8];
    float* out = (float*)d_out;
    float* ws  = (float*)d_ws;

    stats_kernel<<<SBLK, 256, 0, stream>>>(x, ws);
    lstm_kernel<<<B_TOT / NB, 448, 0, stream>>>(x, gamma, beta, W_ih, W_hh,
                                                b_ih, b_hh, W_fc, b_fc, ws, out);
}

// Round 4
// 397.867 us; speedup vs baseline: 5.9040x; 1.4450x over previous
//
#include <hip/hip_runtime.h>
#include <math.h>

#define B_TOT 4096
#define T_LEN 200
#define C_IN  16
#define HH    112
#define G4    448
#define NB    16      // batches per block (= MFMA M)
#define EPS   1e-5f
#define SBLK  256     // stats kernel blocks

typedef _Float16 half8  __attribute__((ext_vector_type(8)));
typedef _Float16 half4v __attribute__((ext_vector_type(4)));
typedef float    f32x4  __attribute__((ext_vector_type(4)));

#define L2E 1.4426950408889634f

// Split fp32 into fp16 hi + 2^12-scaled fp16 lo. Flush hi if it would be a
// fp16 denormal (MFMA denormal behavior unverified); lo then carries the value.
__device__ __forceinline__ void split16(float v, _Float16 &hi, _Float16 &lo) {
    _Float16 h = (_Float16)v;
    float hf = (float)h;
    if (__builtin_fabsf(hf) < 6.103515625e-05f) { h = (_Float16)0.0f; hf = 0.0f; }
    hi = h;
    lo = (_Float16)((v - hf) * 4096.0f);
}

// ---------------- Kernel 1: deterministic per-channel partial sums ----------------
__global__ void stats_kernel(const float* __restrict__ x, float* __restrict__ ws) {
    __shared__ float sm[4][4][8];
    const int tid = threadIdx.x;
    const float4* __restrict__ x4 = (const float4*)x;
    const int total  = B_TOT * T_LEN * C_IN / 4;
    const int stride = SBLK * 256;
    const int i0 = blockIdx.x * 256 + tid;

    float s0=0.f,s1=0.f,s2=0.f,s3=0.f;
    float q0=0.f,q1=0.f,q2=0.f,q3=0.f;
    for (int i = i0; i < total; i += stride) {
        float4 v = x4[i];
        s0 += v.x; q0 += v.x*v.x;
        s1 += v.y; q1 += v.y*v.y;
        s2 += v.z; q2 += v.z*v.z;
        s3 += v.w; q3 += v.w*v.w;
    }
    #pragma unroll
    for (int off = 4; off < 64; off <<= 1) {
        s0 += __shfl_xor(s0, off); q0 += __shfl_xor(q0, off);
        s1 += __shfl_xor(s1, off); q1 += __shfl_xor(q1, off);
        s2 += __shfl_xor(s2, off); q2 += __shfl_xor(q2, off);
        s3 += __shfl_xor(s3, off); q3 += __shfl_xor(q3, off);
    }
    const int lane = tid & 63, wave = tid >> 6;
    if (lane < 4) {
        sm[wave][lane][0] = s0; sm[wave][lane][1] = s1;
        sm[wave][lane][2] = s2; sm[wave][lane][3] = s3;
        sm[wave][lane][4] = q0; sm[wave][lane][5] = q1;
        sm[wave][lane][6] = q2; sm[wave][lane][7] = q3;
    }
    __syncthreads();
    if (tid < 32) {
        const int ch = tid & 15, sq = tid >> 4;
        const int grp = ch >> 2, comp = ch & 3;
        float a = 0.f;
        #pragma unroll
        for (int wv = 0; wv < 4; wv++) a += sm[wv][grp][sq * 4 + comp];
        ws[blockIdx.x * 32 + tid] = a;
    }
}

// ---------------- Kernel 2: MFMA LSTM, one barrier/step ----------------
// 256 blocks x 448 threads (7 waves). Wave w owns the FOUR GATE TILES of
// j-tile w: n = gate*112 + 16w + nloc, gate = 0..3 (i,f,g,o). All four share
// the same D lane mapping -> cell update is in-lane, c in registers.
// v_t = [h_{t-1}; x_t] in LDS in A-fragment order, double-buffered by step parity.
__global__ __launch_bounds__(448, 2) void lstm_kernel(
    const float* __restrict__ x,
    const float* __restrict__ gamma, const float* __restrict__ beta,
    const float* __restrict__ W_ih,  const float* __restrict__ W_hh,
    const float* __restrict__ b_ih,  const float* __restrict__ b_hh,
    const float* __restrict__ W_fc,  const float* __restrict__ b_fc,
    const float* __restrict__ ws,    float* __restrict__ out)
{
    __shared__ float stats_s[32];
    __shared__ float scale_s[16], shift_s[16];
    __shared__ __align__(16) _Float16 vbuf[2][2][4][64][8]; // [plane][hi/lo][kt][lane][8]
    __shared__ __align__(16) float hfinal[NB][HH];

    const int u    = threadIdx.x;
    const int lane = u & 63;
    const int wv   = u >> 6;          // wave = j-tile 0..6
    const int nloc = lane & 15;
    const int q    = lane >> 4;       // 0..3
    const int b0   = blockIdx.x * NB;

    // --- BN stats (deterministic fixed-order reduction) ---
    if (u < 32) {
        float a = 0.f;
        for (int blk = 0; blk < SBLK; ++blk) a += ws[blk * 32 + u];
        stats_s[u] = a;
    }
    __syncthreads();
    if (u < 16) {
        const float N = (float)B_TOT * (float)T_LEN;
        const float mean = stats_s[u] / N;
        const float var  = stats_s[16 + u] / N - mean * mean;
        const float sc   = gamma[u] * rsqrtf(var + EPS);
        scale_s[u] = sc;
        shift_s[u] = beta[u] - mean * sc;
    }
    for (int i = u; i < (int)(sizeof(vbuf) / 4); i += G4) ((int*)vbuf)[i] = 0;
    __syncthreads();

    // --- Register-resident weight fragments (one-time) ---
    // B-fragment: lane (nloc,q) holds W_cat[n][k = kt*32 + q*8 + jj]
    half8 wHI[4][4], wLO[4][4];
    float bpre[4];                    // bias * k1 (activation-prescaled)
    #pragma unroll
    for (int nt = 0; nt < 4; ++nt) {  // nt == gate index
        const int n = nt * HH + wv * 16 + nloc;
        #pragma unroll
        for (int kt = 0; kt < 4; ++kt) {
            const int kb = kt * 32 + q * 8;    // never straddles k=112
            float wtmp[8];
            if (kb < HH) {
                float4 aa = *(const float4*)&W_hh[n * HH + kb];
                float4 bb = *(const float4*)&W_hh[n * HH + kb + 4];
                wtmp[0]=aa.x; wtmp[1]=aa.y; wtmp[2]=aa.z; wtmp[3]=aa.w;
                wtmp[4]=bb.x; wtmp[5]=bb.y; wtmp[6]=bb.z; wtmp[7]=bb.w;
            } else {
                const int c0 = kb - HH;
                float4 aa = *(const float4*)&W_ih[n * C_IN + c0];
                float4 bb = *(const float4*)&W_ih[n * C_IN + c0 + 4];
                wtmp[0]=aa.x*scale_s[c0+0]; wtmp[1]=aa.y*scale_s[c0+1];
                wtmp[2]=aa.z*scale_s[c0+2]; wtmp[3]=aa.w*scale_s[c0+3];
                wtmp[4]=bb.x*scale_s[c0+4]; wtmp[5]=bb.y*scale_s[c0+5];
                wtmp[6]=bb.z*scale_s[c0+6]; wtmp[7]=bb.w*scale_s[c0+7];
            }
            #pragma unroll
            for (int jj = 0; jj < 8; ++jj) {
                _Float16 th, tl;
                split16(wtmp[jj], th, tl);
                wHI[nt][kt][jj] = th;
                wLO[nt][kt][jj] = tl;
            }
        }
        float bb2 = b_ih[n] + b_hh[n];
        #pragma unroll
        for (int c = 0; c < C_IN; ++c) bb2 += W_ih[n * C_IN + c] * shift_s[c];
        const float mg = (nt == 2) ? 2.f : 1.f;
        bpre[nt] = bb2 * (-mg * L2E);
    }

    // --- h write-back mapping (A-fragment address for column jcol) ---
    const int jcol = wv * 16 + nloc;          // 0..111
    const int kt_h = jcol >> 5;
    const int jh   = jcol & 7;
    const int qh16 = ((jcol >> 3) & 3) * 16;  // lane' = b + qh16

    // --- x loader mapping (threads 0..63): b = u>>2, c = 4*(u&3) ---
    const int xb = u >> 2;
    const int xc = (u & 3) * 4;
    const size_t xbase = (size_t)(b0 + xb) * (T_LEN * C_IN) + xc;
    const int jx0 = HH + xc;                  // 112..124
    const int ltx = xb + 16 * ((jx0 >> 3) & 3);
    const int jx  = jx0 & 7;

    float4 xreg;
    if (u < 64) {
        xreg = *(const float4*)&x[xbase];     // x at t=0 -> plane 0
        half4v xh, xl;
        #pragma unroll
        for (int jj = 0; jj < 4; ++jj) {
            _Float16 th, tl;
            split16(((const float*)&xreg)[jj], th, tl);
            xh[jj] = th; xl[jj] = tl;
        }
        *(half4v*)&vbuf[0][0][3][ltx][jx] = xh;
        *(half4v*)&vbuf[0][1][3][ltx][jx] = xl;
    }
    __syncthreads();

    float creg[4] = {0.f, 0.f, 0.f, 0.f};

    for (int step = 0; step < T_LEN; ++step) {
        const int p = step & 1;
        if (u < 64 && step + 1 < T_LEN)
            xreg = *(const float4*)&x[xbase + (size_t)(step + 1) * C_IN];

        f32x4 ch[4], cl[4];
        #pragma unroll
        for (int nt = 0; nt < 4; ++nt) {
            ch[nt] = (f32x4){0.f, 0.f, 0.f, 0.f};
            cl[nt] = (f32x4){0.f, 0.f, 0.f, 0.f};
        }
        #pragma unroll
        for (int kt = 0; kt < 4; ++kt) {
            half8 ah = *(const half8*)&vbuf[p][0][kt][lane][0];
            half8 al = *(const half8*)&vbuf[p][1][kt][lane][0];
            #pragma unroll
            for (int nt = 0; nt < 4; ++nt) {
                ch[nt] = __builtin_amdgcn_mfma_f32_16x16x32_f16(ah, wHI[nt][kt], ch[nt], 0, 0, 0);
                cl[nt] = __builtin_amdgcn_mfma_f32_16x16x32_f16(al, wHI[nt][kt], cl[nt], 0, 0, 0);
                cl[nt] = __builtin_amdgcn_mfma_f32_16x16x32_f16(ah, wLO[nt][kt], cl[nt], 0, 0, 0);
            }
        }

        // Activations: D[b= q*4+r][jcol], gate = nt, all in-lane.
        float act[4][4];
        #pragma unroll
        for (int nt = 0; nt < 4; ++nt) {
            const float mg  = (nt == 2) ? 2.f : 1.f;
            const float k1  = -mg * L2E;
            const float k1s = k1 * (1.f / 4096.f);
            const float dgc = 1.f - mg;
            #pragma unroll
            for (int r = 0; r < 4; ++r) {
                float a = fmaf(ch[nt][r], k1, bpre[nt]);
                a = fmaf(cl[nt][r], k1s, a);
                const float e  = __builtin_amdgcn_exp2f(a);
                const float rr = __builtin_amdgcn_rcpf(1.f + e);
                act[nt][r] = fmaf(mg, rr, dgc);    // sigmoid / tanh
            }
        }

        const bool last = (step + 1 == T_LEN);
        #pragma unroll
        for (int r = 0; r < 4; ++r) {
            const float cn = fmaf(act[1][r], creg[r], act[0][r] * act[2][r]);
            creg[r] = cn;
            const float e2 = __builtin_amdgcn_exp2f(cn * (-2.f * L2E));
            const float th = fmaf(2.f, __builtin_amdgcn_rcpf(1.f + e2), -1.f);
            const float hv = act[3][r] * th;
            if (!last) {
                _Float16 hh, hl;
                split16(hv, hh, hl);
                vbuf[1 - p][0][kt_h][q * 4 + r + qh16][jh] = hh;
                vbuf[1 - p][1][kt_h][q * 4 + r + qh16][jh] = hl;
            } else {
                hfinal[q * 4 + r][jcol] = hv;
            }
        }
        if (u < 64 && step + 1 < T_LEN) {
            half4v xh, xl;
            #pragma unroll
            for (int jj = 0; jj < 4; ++jj) {
                _Float16 th, tl;
                split16(((const float*)&xreg)[jj], th, tl);
                xh[jj] = th; xl[jj] = tl;
            }
            *(half4v*)&vbuf[1 - p][0][3][ltx][jx] = xh;
            *(half4v*)&vbuf[1 - p][1][3][ltx][jx] = xl;
        }
        __syncthreads();
    }

    // --- FC head ---
    if (u < NB * 6) {
        const int b = u / 6, o = u - b * 6;
        float a = b_fc[o];
        for (int j = 0; j < HH; ++j) a += hfinal[b][j] * W_fc[o * HH + j];
        out[(size_t)(b0 + b) * 6 + o] = tanhf(a);
    }
}

extern "C" void kernel_launch(void* const* d_in, const int* in_sizes, int n_in,
                              void* d_out, int out_size, void* d_ws, size_t ws_size,
                              hipStream_t stream) {
    const float* x     = (const float*)d_in[0];
    const float* gamma = (const float*)d_in[1];
    const float* beta  = (const float*)d_in[2];
    const float* W_ih  = (const float*)d_in[3];
    const float* W_hh  = (const float*)d_in[4];
    const float* b_ih  = (const float*)d_in[5];
    const float* b_hh  = (const float*)d_in[6];
    const float* W_fc  = (const float*)d_in[7];
    const float* b_fc  = (const float*)d_in[8];
    float* out = (float*)d_out;
    float* ws  = (float*)d_ws;

    stats_kernel<<<SBLK, 256, 0, stream>>>(x, ws);
    lstm_kernel<<<B_TOT / NB, 448, 0, stream>>>(x, gamma, beta, W_ih, W_hh,
                                                b_ih, b_hh, W_fc, b_fc, ws, out);
}